// Round 4
// baseline (569.638 us; speedup 1.0000x reference)
//
#include <hip/hip_runtime.h>

#define T_STEPS 16
#define H 64
#define S_IN 25
#define A_OUT 4
#define NB 65536

__device__ __forceinline__ float fmaf_(float a, float b, float c) { return __builtin_fmaf(a, b, c); }

// Transpose W2 (64x64) and W3 (4x64) into workspace so the hot loop reads
// contiguous wave-uniform rows.
__global__ void snn_prep(const float* __restrict__ W2, const float* __restrict__ W3,
                         float* __restrict__ W2T, float* __restrict__ W3T) {
    int i = blockIdx.x * blockDim.x + threadIdx.x;
    if (i < H * H) { int h = i >> 6, k = i & 63; W2T[k * H + h] = W2[h * H + k]; }
    if (i < A_OUT * H) { int a = i >> 6, h = i & 63; W3T[h * A_OUT + a] = W3[a * H + h]; }
}

__global__ __launch_bounds__(256) void snn_main(
    const float* __restrict__ x,
    const float* __restrict__ W1, const float* __restrict__ b1,
    const float* __restrict__ W2T, const float* __restrict__ b2,
    const float* __restrict__ W3T, const float* __restrict__ b3,
    float* __restrict__ out, int* __restrict__ g_pre, int* __restrict__ g_post)
{
#pragma clang fp contract(off)
    __shared__ float w2s[H * H];         // 16 KB: W2T staged once; k-loop reads are
                                         // wave-broadcast ds_read_b128 (conflict-free),
                                         // prefetchable into VGPRs (SGPRs can't hold a row)
    __shared__ int lds_pre[T_STEPS * H];
    __shared__ int lds_post[T_STEPS * A_OUT];
    for (int i = threadIdx.x; i < (H * H) / 4; i += 256)
        reinterpret_cast<float4*>(w2s)[i] = reinterpret_cast<const float4*>(W2T)[i];
    for (int i = threadIdx.x; i < T_STEPS * H; i += 256) lds_pre[i] = 0;
    if (threadIdx.x < T_STEPS * A_OUT) lds_post[threadIdx.x] = 0;
    __syncthreads();

    const int b = blockIdx.x * 256 + threadIdx.x;   // one thread = one batch element
    const int lane = threadIdx.x & 63;

    // cur1 = x @ W1.T + b1  (identical every timestep)
    float cur1[H];
    {
        float xv[S_IN];
        #pragma unroll
        for (int s = 0; s < S_IN; ++s) xv[s] = x[b * S_IN + s];
        #pragma unroll
        for (int h = 0; h < H; ++h) {
            float acc = 0.0f;
            #pragma unroll
            for (int s = 0; s < S_IN; ++s) acc = fmaf_(xv[s], W1[h * S_IN + s], acc);
            cur1[h] = acc + b1[h];
        }
    }

    float m1[H], m2[H];
    float m3[A_OUT], accs[A_OUT];
    #pragma unroll
    for (int h = 0; h < H; ++h) { m1[h] = 0.0f; m2[h] = 0.0f; }
    #pragma unroll
    for (int a = 0; a < A_OUT; ++a) { m3[a] = 0.0f; accs[a] = 0.0f; }

    for (int t = 0; t < T_STEPS; ++t) {
        // ---- layer 1: membrane + spike, pack spikes into a 64-bit mask ----
        unsigned long long s1mask = 0ull;
        #pragma unroll
        for (int h = 0; h < H; ++h) {
            float m = 0.95f * m1[h];
            m = m + cur1[h];
            bool sp = m > 1.0f;
            m1[h] = sp ? (m - 1.0f) : m;
            s1mask |= ((unsigned long long)(sp ? 1u : 0u)) << h;
        }

        // ---- layer 2: m2 = beta*m2 + s1 @ W2.T (exact FMA chain, k-order) ----
        #pragma unroll
        for (int h = 0; h < H; ++h) m2[h] = 0.95f * m2[h];
        // unroll 2: ~1 KB body (no I$ thrash), one row of ds_read lookahead;
        // broadcast reads, compiler's fine-grained lgkmcnt pipelines them.
        #pragma unroll 2
        for (int k = 0; k < H; ++k) {
            float s1f = (float)((s1mask >> k) & 1ull);
            const float4* wr = reinterpret_cast<const float4*>(w2s + k * H);
            #pragma unroll
            for (int q = 0; q < H / 4; ++q) {
                float4 w = wr[q];
                m2[4*q+0] = fmaf_(s1f, w.x, m2[4*q+0]);   // exact: s1f in {0,1};
                m2[4*q+1] = fmaf_(s1f, w.y, m2[4*q+1]);   // per-h chain order over k
                m2[4*q+2] = fmaf_(s1f, w.z, m2[4*q+2]);   // identical to reference
                m2[4*q+3] = fmaf_(s1f, w.w, m2[4*q+3]);
            }
        }

        // ---- layer 2 spikes, layer 3 accumulation, pre-counts ----
        #pragma unroll
        for (int a = 0; a < A_OUT; ++a) m3[a] = 0.95f * m3[a];
        int myCnt = 0;
        #pragma unroll
        for (int h = 0; h < H; ++h) {
            float m = m2[h] + b2[h];
            bool sp = m > 1.0f;
            float s2f = sp ? 1.0f : 0.0f;
            m2[h] = m - s2f;
            #pragma unroll
            for (int a = 0; a < A_OUT; ++a)
                m3[a] = fmaf_(s2f, W3T[h * A_OUT + a], m3[a]);            // exact: s2f in {0,1}
            int cnt = (int)__popcll(__ballot(sp));    // wave-uniform spike count for hidden unit h
            myCnt = (lane == h) ? cnt : myCnt;        // lane h keeps unit h's count (v_cndmask)
        }

        // ---- layer 3 spikes + post-counts + readout accumulation ----
        int myPost = 0;
        #pragma unroll
        for (int a = 0; a < A_OUT; ++a) {
            float m = m3[a] + b3[a];
            bool sp = m > 1.0f;
            float s3f = sp ? 1.0f : 0.0f;
            m3[a] = m - s3f;
            accs[a] = accs[a] + s3f;
            int cnt = (int)__popcll(__ballot(sp));
            myPost = (lane == a) ? cnt : myPost;
        }

        atomicAdd(&lds_pre[t * H + lane], myCnt);
        if (lane < A_OUT) atomicAdd(&lds_post[t * A_OUT + lane], myPost);
    }

    // ---- per-batch softmax(acc/16) ----
    {
        float r0 = accs[0] * 0.0625f, r1 = accs[1] * 0.0625f;
        float r2 = accs[2] * 0.0625f, r3 = accs[3] * 0.0625f;
        float mx = fmaxf(fmaxf(r0, r1), fmaxf(r2, r3));
        float e0 = expf(r0 - mx), e1 = expf(r1 - mx);
        float e2 = expf(r2 - mx), e3 = expf(r3 - mx);
        float s = ((e0 + e1) + e2) + e3;
        float4 p = make_float4(e0 / s, e1 / s, e2 / s, e3 / s);
        reinterpret_cast<float4*>(out)[b] = p;
    }

    __syncthreads();
    for (int i = threadIdx.x; i < T_STEPS * H; i += 256) atomicAdd(&g_pre[i], lds_pre[i]);
    if (threadIdx.x < T_STEPS * A_OUT) atomicAdd(&g_post[threadIdx.x], lds_post[threadIdx.x]);
}

// elig_t = 0.95*elig_{t-1} + (A_PLUS-A_MINUS) * outer(post_t, pre_t); means are exact counts/B.
__global__ void snn_elig(const int* __restrict__ g_pre, const int* __restrict__ g_post,
                         const float* __restrict__ elig0, float* __restrict__ out) {
#pragma clang fp contract(off)
    int i = threadIdx.x;                 // 256 = A_OUT * H
    int a = i >> 6, h = i & 63;
    float e = elig0[i];
    const float invB = 1.0f / 65536.0f;
    for (int t = 0; t < T_STEPS; ++t) {
        float pre  = (float)g_pre[t * H + h] * invB;
        float post = (float)g_post[t * A_OUT + a] * invB;
        e = 0.95f * e + (-0.002f) * (post * pre);
    }
    out[NB * A_OUT + i] = e;
}

extern "C" void kernel_launch(void* const* d_in, const int* in_sizes, int n_in,
                              void* d_out, int out_size, void* d_ws, size_t ws_size,
                              hipStream_t stream) {
    const float* x     = (const float*)d_in[0];
    const float* W1    = (const float*)d_in[1];
    const float* b1    = (const float*)d_in[2];
    const float* W2    = (const float*)d_in[3];
    const float* b2    = (const float*)d_in[4];
    const float* W3    = (const float*)d_in[5];
    const float* b3    = (const float*)d_in[6];
    const float* elig0 = (const float*)d_in[7];
    float* out = (float*)d_out;

    char* ws = (char*)d_ws;
    int*   g_pre  = (int*)(ws);                    // 1024 ints
    int*   g_post = (int*)(ws + 4096);             // 64 ints
    float* W2T    = (float*)(ws + 8192);           // 4096 floats
    float* W3T    = (float*)(ws + 8192 + 16384);   // 256 floats

    (void)hipMemsetAsync(ws, 0, 4096 + 256, stream);  // zero count accumulators every launch
    snn_prep<<<17, 256, 0, stream>>>(W2, W3, W2T, W3T);
    snn_main<<<NB / 256, 256, 0, stream>>>(x, W1, b1, W2T, b2, W3T, b3, out, g_pre, g_post);
    snn_elig<<<1, 256, 0, stream>>>(g_pre, g_post, elig0, out);
}

// Round 5
// 204.294 us; speedup vs baseline: 2.7883x; 2.7883x over previous
//
#include <hip/hip_runtime.h>

#define T_STEPS 16
#define H 64
#define S_IN 25
#define A_OUT 4
#define NB 65536
#define UPW 16            // units per thread (H / 4 waves)
#define EPB 64            // batch elements per block (one per lane)

__device__ __forceinline__ float fmaf_(float a, float b, float c) { return __builtin_fmaf(a, b, c); }

// Transpose W2 (64x64) and W3 (4x64) into workspace so the hot loop reads
// contiguous wave-uniform rows.
__global__ void snn_prep(const float* __restrict__ W2, const float* __restrict__ W3,
                         float* __restrict__ W2T, float* __restrict__ W3T) {
    int i = blockIdx.x * blockDim.x + threadIdx.x;
    if (i < H * H) { int h = i >> 6, k = i & 63; W2T[k * H + h] = W2[h * H + k]; }
    if (i < A_OUT * H) { int a = i >> 6, h = i & 63; W3T[h * A_OUT + a] = W3[a * H + h]; }
}

// 4 threads per batch element (one per wave), 64 elements per block.
// 1024 blocks * 256 thr = 4 waves/SIMD -> TLP hides the uniform weight-load
// latency that single-wave occupancy (R2-R4) could not.
__global__ __launch_bounds__(256, 4) void snn_main(
    const float* __restrict__ x,
    const float* __restrict__ W1, const float* __restrict__ b1,
    const float* __restrict__ W2T, const float* __restrict__ b2,
    const float* __restrict__ W3T, const float* __restrict__ b3,
    float* __restrict__ out, int* __restrict__ g_pre, int* __restrict__ g_post)
{
#pragma clang fp contract(off)
    __shared__ unsigned int s1buf[2][4][EPB];   // [slot][wave][elem] 16-bit quarter masks
    __shared__ unsigned int s2buf[2][4][EPB];
    __shared__ float m3acc[EPB][8];             // [elem][0..3]=m3, [4..7]=acc
    __shared__ int lds_pre[T_STEPS * H];
    __shared__ int lds_post[T_STEPS * A_OUT];

    for (int i = threadIdx.x; i < T_STEPS * H; i += 256) lds_pre[i] = 0;
    if (threadIdx.x < T_STEPS * A_OUT) lds_post[threadIdx.x] = 0;
    for (int i = threadIdx.x; i < EPB * 8; i += 256) (&m3acc[0][0])[i] = 0.0f;

    const int lane  = threadIdx.x & 63;
    const int wq    = __builtin_amdgcn_readfirstlane(threadIdx.x >> 6);  // wave id 0..3 (SGPR)
    const int hbase = UPW * wq;                                          // this wave's unit range
    const int b     = blockIdx.x * EPB + lane;                           // batch element

    // cur1 for this thread's 16 units (same s-chain as reference)
    float cur1[UPW];
    {
        float xv[S_IN];
        #pragma unroll
        for (int s = 0; s < S_IN; ++s) xv[s] = x[b * S_IN + s];
        #pragma unroll
        for (int j = 0; j < UPW; ++j) {
            int h = hbase + j;
            float acc = 0.0f;
            #pragma unroll
            for (int s = 0; s < S_IN; ++s) acc = fmaf_(xv[s], W1[h * S_IN + s], acc);
            cur1[j] = acc + b1[h];
        }
    }

    float m1[UPW], m2[UPW];
    #pragma unroll
    for (int j = 0; j < UPW; ++j) { m1[j] = 0.0f; m2[j] = 0.0f; }

    // ---- prologue: layer-1 at t=0 ----
    {
        unsigned int s1loc = 0u;
        #pragma unroll
        for (int j = 0; j < UPW; ++j) {
            float m = 0.95f * m1[j];
            m = m + cur1[j];
            bool sp = m > 1.0f;
            m1[j] = sp ? (m - 1.0f) : m;
            s1loc |= (sp ? 1u : 0u) << j;
        }
        s1buf[0][wq][lane] = s1loc;
    }
    __syncthreads();

    float ac_final[A_OUT];   // valid in wave 3 after t=15
    #pragma unroll
    for (int a = 0; a < A_OUT; ++a) ac_final[a] = 0.0f;

    for (int t = 0; t < T_STEPS; ++t) {
        const int slot = t & 1;

        // ---- layer 2: full s1 mask from LDS, k-chain over own 16 units ----
        unsigned int p0 = s1buf[slot][0][lane], p1 = s1buf[slot][1][lane];
        unsigned int p2 = s1buf[slot][2][lane], p3 = s1buf[slot][3][lane];
        unsigned long long msk = (unsigned long long)(p0 | (p1 << 16))
                               | ((unsigned long long)(p2 | (p3 << 16)) << 32);
        #pragma unroll
        for (int j = 0; j < UPW; ++j) m2[j] = 0.95f * m2[j];
        for (int k = 0; k < H; ++k) {            // k ascending: exact chain order of R2
            float s1f = (float)((unsigned int)msk & 1u);
            msk >>= 1;
            const float* wr = W2T + (k << 6) + hbase;   // wave-uniform 64B segment
            #pragma unroll
            for (int j = 0; j < UPW; ++j) m2[j] = fmaf_(s1f, wr[j], m2[j]);
        }

        // ---- layer-2 spikes + pre-counts (this wave's units, all 64 elems) ----
        unsigned int s2loc = 0u;
        int myCnt = 0;
        #pragma unroll
        for (int j = 0; j < UPW; ++j) {
            float m = m2[j] + b2[hbase + j];
            bool sp = m > 1.0f;
            float s2f = sp ? 1.0f : 0.0f;
            m2[j] = m - s2f;
            s2loc |= (sp ? 1u : 0u) << j;
            int cnt = (int)__popcll(__ballot(sp));
            myCnt = (lane == j) ? cnt : myCnt;
        }
        s2buf[slot][wq][lane] = s2loc;
        if (lane < UPW) lds_pre[t * H + hbase + lane] = myCnt;  // single writer per slot

        // ---- layer 1 for t+1 (independent of layer 3) ----
        if (t < T_STEPS - 1) {
            unsigned int s1loc = 0u;
            #pragma unroll
            for (int j = 0; j < UPW; ++j) {
                float m = 0.95f * m1[j];
                m = m + cur1[j];
                bool sp = m > 1.0f;
                m1[j] = sp ? (m - 1.0f) : m;
                s1loc |= (sp ? 1u : 0u) << j;
            }
            s1buf[slot ^ 1][wq][lane] = s1loc;
        }
        __syncthreads();

        // ---- layer 3: rotating duty wave (balances SIMDs), exact h-chain ----
        if (wq == (t & 3)) {
            unsigned int q0 = s2buf[slot][0][lane], q1 = s2buf[slot][1][lane];
            unsigned int q2 = s2buf[slot][2][lane], q3 = s2buf[slot][3][lane];
            unsigned long long s2m = (unsigned long long)(q0 | (q1 << 16))
                                   | ((unsigned long long)(q2 | (q3 << 16)) << 32);
            float m3[A_OUT], ac[A_OUT];
            #pragma unroll
            for (int a = 0; a < A_OUT; ++a) { m3[a] = 0.95f * m3acc[lane][a]; ac[a] = m3acc[lane][4 + a]; }
            for (int h = 0; h < H; ++h) {        // h ascending: exact chain order of R2
                float s2f = (float)((unsigned int)s2m & 1u);
                s2m >>= 1;
                const float4 w = *reinterpret_cast<const float4*>(W3T + h * A_OUT); // uniform 16B
                m3[0] = fmaf_(s2f, w.x, m3[0]);
                m3[1] = fmaf_(s2f, w.y, m3[1]);
                m3[2] = fmaf_(s2f, w.z, m3[2]);
                m3[3] = fmaf_(s2f, w.w, m3[3]);
            }
            int myPost = 0;
            #pragma unroll
            for (int a = 0; a < A_OUT; ++a) {
                float m = m3[a] + b3[a];
                bool sp = m > 1.0f;
                float s3f = sp ? 1.0f : 0.0f;
                m3[a] = m - s3f;
                ac[a] = ac[a] + s3f;
                int cnt = (int)__popcll(__ballot(sp));
                myPost = (lane == a) ? cnt : myPost;
            }
            if (lane < A_OUT) lds_post[t * A_OUT + lane] = myPost;
            if (t == T_STEPS - 1) {
                #pragma unroll
                for (int a = 0; a < A_OUT; ++a) ac_final[a] = ac[a];
            } else {
                #pragma unroll
                for (int a = 0; a < A_OUT; ++a) { m3acc[lane][a] = m3[a]; m3acc[lane][4 + a] = ac[a]; }
            }
        }
    }

    // ---- softmax (wave 3 holds final acc after duty t=15) ----
    if (wq == 3) {
        float r0 = ac_final[0] * 0.0625f, r1 = ac_final[1] * 0.0625f;
        float r2 = ac_final[2] * 0.0625f, r3 = ac_final[3] * 0.0625f;
        float mx = fmaxf(fmaxf(r0, r1), fmaxf(r2, r3));
        float e0 = expf(r0 - mx), e1 = expf(r1 - mx);
        float e2 = expf(r2 - mx), e3 = expf(r3 - mx);
        float s = ((e0 + e1) + e2) + e3;
        reinterpret_cast<float4*>(out)[b] = make_float4(e0 / s, e1 / s, e2 / s, e3 / s);
    }

    __syncthreads();
    for (int i = threadIdx.x; i < T_STEPS * H; i += 256) atomicAdd(&g_pre[i], lds_pre[i]);
    if (threadIdx.x < T_STEPS * A_OUT) atomicAdd(&g_post[threadIdx.x], lds_post[threadIdx.x]);
}

// elig_t = 0.95*elig_{t-1} + (A_PLUS-A_MINUS) * outer(post_t, pre_t); means are exact counts/B.
__global__ void snn_elig(const int* __restrict__ g_pre, const int* __restrict__ g_post,
                         const float* __restrict__ elig0, float* __restrict__ out) {
#pragma clang fp contract(off)
    int i = threadIdx.x;                 // 256 = A_OUT * H
    int a = i >> 6, h = i & 63;
    float e = elig0[i];
    const float invB = 1.0f / 65536.0f;
    for (int t = 0; t < T_STEPS; ++t) {
        float pre  = (float)g_pre[t * H + h] * invB;
        float post = (float)g_post[t * A_OUT + a] * invB;
        e = 0.95f * e + (-0.002f) * (post * pre);
    }
    out[NB * A_OUT + i] = e;
}

extern "C" void kernel_launch(void* const* d_in, const int* in_sizes, int n_in,
                              void* d_out, int out_size, void* d_ws, size_t ws_size,
                              hipStream_t stream) {
    const float* x     = (const float*)d_in[0];
    const float* W1    = (const float*)d_in[1];
    const float* b1    = (const float*)d_in[2];
    const float* W2    = (const float*)d_in[3];
    const float* b2    = (const float*)d_in[4];
    const float* W3    = (const float*)d_in[5];
    const float* b3    = (const float*)d_in[6];
    const float* elig0 = (const float*)d_in[7];
    float* out = (float*)d_out;

    char* ws = (char*)d_ws;
    int*   g_pre  = (int*)(ws);                    // 1024 ints
    int*   g_post = (int*)(ws + 4096);             // 64 ints
    float* W2T    = (float*)(ws + 8192);           // 4096 floats
    float* W3T    = (float*)(ws + 8192 + 16384);   // 256 floats

    (void)hipMemsetAsync(ws, 0, 4096 + 256, stream);  // zero count accumulators every launch
    snn_prep<<<17, 256, 0, stream>>>(W2, W3, W2T, W3T);
    snn_main<<<NB / EPB, 256, 0, stream>>>(x, W1, b1, W2T, b2, W3T, b3, out, g_pre, g_post);
    snn_elig<<<1, 256, 0, stream>>>(g_pre, g_post, elig0, out);
}